// Round 1
// baseline (332.130 us; speedup 1.0000x reference)
//
#include <hip/hip_runtime.h>
#include <hip/hip_bf16.h>

// Problem constants
#define B_     16384
#define NS_    26
#define ND_    13
#define V_     100000
#define E_     16
#define H_     400
#define HP     416     // padded hidden (multiple of 32)
#define K0P    448     // padded DNN_IN (429 -> 448, multiple of 32)

typedef __bf16 bf16x8 __attribute__((ext_vector_type(8)));
typedef float  f32x4  __attribute__((ext_vector_type(4)));

__device__ __forceinline__ unsigned short f2bf(float f) {
  __hip_bfloat16 h = __float2bfloat16(f);
  return __builtin_bit_cast(unsigned short, h);
}
__device__ __forceinline__ float bf2f(unsigned short u) {
  unsigned v = ((unsigned)u) << 16;
  return __builtin_bit_cast(float, v);
}

// ---------------------------------------------------------------------------
// FM part + build bf16 dnn_in (padded to 448). 16 lanes per batch row.
// Writes partial logit = bias + linear_sparse + linear_dense + cross to out.
// ---------------------------------------------------------------------------
__global__ __launch_bounds__(256) void fm_kernel(
    const int* __restrict__ Xs, const float* __restrict__ Xd,
    const float* __restrict__ emb1, const float* __restrict__ emb2,
    const float* __restrict__ linw, const float* __restrict__ bias,
    unsigned short* __restrict__ dnn, float* __restrict__ out) {
  const int row  = blockIdx.x * 16 + (threadIdx.x >> 4);
  const int lane = threadIdx.x & 15;
  const int* xs = Xs + row * NS_;
  unsigned short* drow = dnn + (size_t)row * K0P;

  float s_sum = 0.f, s_sq = 0.f;
#pragma unroll
  for (int f = 0; f < NS_; ++f) {
    int idx = xs[f];
    float v = emb2[((size_t)f * V_ + idx) * E_ + lane];
    s_sum += v;
    s_sq  += v * v;
    drow[f * 16 + lane] = f2bf(v);
  }

  // linear sparse: each lane covers features lane, lane+16
  float lin = 0.f;
  for (int f = lane; f < NS_; f += 16)
    lin += emb1[(size_t)f * V_ + xs[f]];

  // linear dense + dense part of dnn_in
  float xdv = 0.f;
  if (lane < ND_) {
    xdv = Xd[row * ND_ + lane];
    lin += xdv * linw[lane];
  }
  drow[416 + lane] = f2bf(lane < ND_ ? xdv : 0.f);  // 416..428 dense, 429..431 zero
  drow[432 + lane] = 0;                             // 432..447 zero pad

  float r = 0.5f * (s_sum * s_sum - s_sq) + lin;
#pragma unroll
  for (int m = 8; m >= 1; m >>= 1) r += __shfl_xor(r, m, 64);
  if (lane == 0) out[row] = r + bias[0];
}

// ---------------------------------------------------------------------------
// Weight conversion: W [K][400] fp32 row-major -> Wt [416][Kp] bf16 with
// Wt[n*Kp + k] = W[k*400 + n], zero-padded. i iterates k-major (coalesced read).
// ---------------------------------------------------------------------------
__global__ __launch_bounds__(256) void conv_w(
    const float* __restrict__ W, unsigned short* __restrict__ Wt, int K, int Kp) {
  int i = blockIdx.x * 256 + threadIdx.x;
  int total = Kp * HP;
  if (i >= total) return;
  int k = i / HP;
  int n = i - k * HP;
  float v = (k < K && n < H_) ? W[k * H_ + n] : 0.f;
  Wt[(size_t)n * Kp + k] = f2bf(v);
}

__global__ void pad_bias(const float* __restrict__ b, float* __restrict__ bp) {
  int i = blockIdx.x * 256 + threadIdx.x;
  if (i < HP) bp[i] = (i < H_) ? b[i] : 0.f;
}

// ---------------------------------------------------------------------------
// C[M][416] = relu(A[M][K] @ B[K][416] + bias), all bf16 except bias/acc fp32.
// Bt is B transposed: Bt[n][k]. Block tile 64x32, BK=32, 4 waves.
// ---------------------------------------------------------------------------
__global__ __launch_bounds__(256) void gemm_relu(
    const unsigned short* __restrict__ A, const unsigned short* __restrict__ Bt,
    const float* __restrict__ bias, unsigned short* __restrict__ C, int K) {
  __shared__ unsigned short As[64][40];   // stride 40 -> 80B rows, 16B aligned, low conflict
  __shared__ unsigned short Bs[32][40];

  const int tid  = threadIdx.x;
  const int wave = tid >> 6;
  const int lane = tid & 63;
  const int quad = lane >> 4;
  const int l16  = lane & 15;
  const int rowBase = blockIdx.x * 64;
  const int colBase = blockIdx.y * 32;

  // staging assignments
  const int ar = tid >> 2, aseg = tid & 3;   // A: 64 rows x 4 segs of 8 bf16
  const int bn = tid >> 3, bseg = tid & 7;   // B: 32 rows x 8 segs of 4 bf16

  const unsigned short* aptr = A  + (size_t)(rowBase + ar) * K + aseg * 8;
  const unsigned short* bptr = Bt + (size_t)(colBase + bn) * K + bseg * 4;

  f32x4 acc0 = {0.f, 0.f, 0.f, 0.f};
  f32x4 acc1 = {0.f, 0.f, 0.f, 0.f};

  const int nK = K >> 5;
  for (int kt = 0; kt < nK; ++kt) {
    uint4 av = *(const uint4*)(aptr + kt * 32);
    uint2 bv = *(const uint2*)(bptr + kt * 32);
    __syncthreads();
    *(uint4*)&As[ar][aseg * 8] = av;
    *(uint2*)&Bs[bn][bseg * 4] = bv;
    __syncthreads();

    uint4 au  = *(const uint4*)&As[wave * 16 + l16][quad * 8];
    uint4 b0u = *(const uint4*)&Bs[l16][quad * 8];
    uint4 b1u = *(const uint4*)&Bs[16 + l16][quad * 8];
    bf16x8 af  = __builtin_bit_cast(bf16x8, au);
    bf16x8 bf0 = __builtin_bit_cast(bf16x8, b0u);
    bf16x8 bf1 = __builtin_bit_cast(bf16x8, b1u);
    acc0 = __builtin_amdgcn_mfma_f32_16x16x32_bf16(af, bf0, acc0, 0, 0, 0);
    acc1 = __builtin_amdgcn_mfma_f32_16x16x32_bf16(af, bf1, acc1, 0, 0, 0);
  }

#pragma unroll
  for (int t = 0; t < 2; ++t) {
    f32x4 a = (t == 0) ? acc0 : acc1;
    int col = colBase + t * 16 + l16;
    float bz = bias[col];
#pragma unroll
    for (int r = 0; r < 4; ++r) {
      int row = rowBase + wave * 16 + quad * 4 + r;
      float v = a[r] + bz;
      v = v > 0.f ? v : 0.f;
      C[(size_t)row * HP + col] = f2bf(v);
    }
  }
}

// ---------------------------------------------------------------------------
// logit += h2 . W_out  (one wave per row)
// ---------------------------------------------------------------------------
__global__ __launch_bounds__(256) void out_dot(
    const unsigned short* __restrict__ h2, const float* __restrict__ Wout,
    float* __restrict__ out) {
  const int row  = blockIdx.x * 4 + (threadIdx.x >> 6);
  const int lane = threadIdx.x & 63;
  const unsigned short* hr = h2 + (size_t)row * HP;
  float s = 0.f;
  for (int c = lane; c < H_; c += 64) s += bf2f(hr[c]) * Wout[c];
#pragma unroll
  for (int m = 32; m >= 1; m >>= 1) s += __shfl_xor(s, m, 64);
  if (lane == 0) out[row] += s;
}

// ---------------------------------------------------------------------------
extern "C" void kernel_launch(void* const* d_in, const int* in_sizes, int n_in,
                              void* d_out, int out_size, void* d_ws, size_t ws_size,
                              hipStream_t stream) {
  const int*   Xs   = (const int*)d_in[0];
  const float* Xd   = (const float*)d_in[1];
  const float* emb1 = (const float*)d_in[2];
  const float* emb2 = (const float*)d_in[3];
  const float* linw = (const float*)d_in[4];
  const float* bias = (const float*)d_in[5];
  const float* W0   = (const float*)d_in[6];
  const float* b0   = (const float*)d_in[7];
  const float* W1   = (const float*)d_in[8];
  const float* b1   = (const float*)d_in[9];
  const float* W2   = (const float*)d_in[10];
  const float* b2   = (const float*)d_in[11];
  const float* Wout = (const float*)d_in[12];
  float* out = (float*)d_out;

  char* ws = (char*)d_ws;
  // P0: dnn_in [16384][448] bf16, later reused for h1 [16384][416]
  // P1: h0 [16384][416] bf16, later reused for h2
  unsigned short* P0  = (unsigned short*)(ws);
  unsigned short* P1  = (unsigned short*)(ws + 14680064);
  unsigned short* W0t = (unsigned short*)(ws + 28311552);   // [416][448]
  unsigned short* W1t = (unsigned short*)(ws + 28684288);   // [416][416]
  unsigned short* W2t = (unsigned short*)(ws + 29030400);   // [416][416]
  float* b0p = (float*)(ws + 29376512);
  float* b1p = (float*)(ws + 29378176);
  float* b2p = (float*)(ws + 29379840);

  fm_kernel<<<B_ / 16, 256, 0, stream>>>(Xs, Xd, emb1, emb2, linw, bias, P0, out);

  conv_w<<<(K0P * HP + 255) / 256, 256, 0, stream>>>(W0, W0t, 429, K0P);
  conv_w<<<(HP * HP + 255) / 256, 256, 0, stream>>>(W1, W1t, 400, HP);
  conv_w<<<(HP * HP + 255) / 256, 256, 0, stream>>>(W2, W2t, 400, HP);
  pad_bias<<<2, 256, 0, stream>>>(b0, b0p);
  pad_bias<<<2, 256, 0, stream>>>(b1, b1p);
  pad_bias<<<2, 256, 0, stream>>>(b2, b2p);

  dim3 grid(B_ / 64, HP / 32);
  gemm_relu<<<grid, 256, 0, stream>>>(P0, W0t, b0p, P1, K0P);  // h0
  gemm_relu<<<grid, 256, 0, stream>>>(P1, W1t, b1p, P0, HP);   // h1
  gemm_relu<<<grid, 256, 0, stream>>>(P0, W2t, b2p, P1, HP);   // h2

  out_dot<<<B_ / 4, 256, 0, stream>>>(P1, Wout, out);
}

// Round 2
// 297.013 us; speedup vs baseline: 1.1182x; 1.1182x over previous
//
#include <hip/hip_runtime.h>
#include <hip/hip_bf16.h>

// Problem constants
#define B_     16384
#define NS_    26
#define ND_    13
#define V_     100000
#define E_     16
#define H_     400
#define NP     448     // padded N and K for every DNN layer (429->448, 400->448)
#define K0A    429     // actual DNN_IN

typedef __bf16 bf16x8 __attribute__((ext_vector_type(8)));
typedef float  f32x4  __attribute__((ext_vector_type(4)));

__device__ __forceinline__ unsigned short f2bf(float f) {
  __hip_bfloat16 h = __float2bfloat16(f);
  return __builtin_bit_cast(unsigned short, h);
}

// ---------------------------------------------------------------------------
// FM part + build bf16 dnn_in (padded to 448). 16 lanes per batch row.
// out[row] = bias + linear_sparse + linear_dense + cross   (written with =)
// ---------------------------------------------------------------------------
__global__ __launch_bounds__(256) void fm_kernel(
    const int* __restrict__ Xs, const float* __restrict__ Xd,
    const float* __restrict__ emb1, const float* __restrict__ emb2,
    const float* __restrict__ linw, const float* __restrict__ bias,
    unsigned short* __restrict__ dnn, float* __restrict__ out) {
  const int row  = blockIdx.x * 16 + (threadIdx.x >> 4);
  const int lane = threadIdx.x & 15;
  const int* xs = Xs + row * NS_;
  unsigned short* drow = dnn + (size_t)row * NP;

  float s_sum = 0.f, s_sq = 0.f;
#pragma unroll
  for (int f = 0; f < NS_; ++f) {
    int idx = xs[f];
    float v = emb2[((size_t)f * V_ + idx) * E_ + lane];
    s_sum += v;
    s_sq  += v * v;
    drow[f * 16 + lane] = f2bf(v);
  }

  // linear sparse: each lane covers features lane, lane+16
  float lin = 0.f;
  for (int f = lane; f < NS_; f += 16)
    lin += emb1[(size_t)f * V_ + xs[f]];

  // linear dense + dense part of dnn_in
  float xdv = 0.f;
  if (lane < ND_) {
    xdv = Xd[row * ND_ + lane];
    lin += xdv * linw[lane];
  }
  drow[416 + lane] = f2bf(lane < ND_ ? xdv : 0.f);  // 416..428 dense, 429..431 zero
  drow[432 + lane] = 0;                             // 432..447 zero pad

  float r = 0.5f * (s_sum * s_sum - s_sq) + lin;
#pragma unroll
  for (int m = 8; m >= 1; m >>= 1) r += __shfl_xor(r, m, 64);
  if (lane == 0) out[row] = r + bias[0];
}

// ---------------------------------------------------------------------------
// One launch: transpose+pad all three weight matrices to bf16 [448][448]
// (Wt[n*448+k] = W[k*H + n]) and pad the three biases + W_out to 448 fp32.
// Reads are k-major (coalesced); writes strided (small, L2-resident).
// ---------------------------------------------------------------------------
__global__ __launch_bounds__(256) void conv_all(
    const float* __restrict__ W0, const float* __restrict__ W1,
    const float* __restrict__ W2, const float* __restrict__ b0,
    const float* __restrict__ b1, const float* __restrict__ b2,
    const float* __restrict__ Wout,
    unsigned short* __restrict__ W0t, unsigned short* __restrict__ W1t,
    unsigned short* __restrict__ W2t, float* __restrict__ b0p,
    float* __restrict__ b1p, float* __restrict__ b2p,
    float* __restrict__ woutp) {
  const int WSZ = NP * NP;  // 200704
  int i = blockIdx.x * 256 + threadIdx.x;
  if (i < 3 * WSZ) {
    int which = i / WSZ;
    int j = i - which * WSZ;
    int k = j / NP, n = j - (j / NP) * NP;
    const float* W = (which == 0) ? W0 : (which == 1) ? W1 : W2;
    unsigned short* Wt = (which == 0) ? W0t : (which == 1) ? W1t : W2t;
    int Kact = (which == 0) ? K0A : H_;
    float v = (k < Kact && n < H_) ? W[k * H_ + n] : 0.f;
    Wt[(size_t)n * NP + k] = f2bf(v);
  } else {
    int j = i - 3 * WSZ;
    if (j < NP)          b0p[j]            = (j < H_) ? b0[j] : 0.f;
    else if (j < 2 * NP) b1p[j - NP]       = (j - NP < H_) ? b1[j - NP] : 0.f;
    else if (j < 3 * NP) b2p[j - 2 * NP]   = (j - 2 * NP < H_) ? b2[j - 2 * NP] : 0.f;
    else if (j < 4 * NP) woutp[j - 3 * NP] = (j - 3 * NP < H_) ? Wout[j - 3 * NP] : 0.f;
  }
}

// ---------------------------------------------------------------------------
// C[M][448] = relu(A[M][448] @ B[448][448] + bias). Bt is B transposed.
// Block tile 128x64, BK=32, 4 waves; each wave computes 32x64 (2x4 MFMA frags).
// Register prefetch of tile k+1 overlaps global latency with MFMA.
// fuse!=0: skip C write, instead logit[row] += sum_col relu(v)*wout[col]
// (per-row shuffle reduce + atomicAdd; cols>=400 have wout padded to 0).
// ---------------------------------------------------------------------------
__global__ __launch_bounds__(256) void gemm_relu(
    const unsigned short* __restrict__ A, const unsigned short* __restrict__ Bt,
    const float* __restrict__ bias, unsigned short* __restrict__ C,
    const float* __restrict__ wout, float* __restrict__ out, int fuse) {
  __shared__ unsigned short As[128][40];  // 80B rows: 16B aligned, 2-way (free) on b128
  __shared__ unsigned short Bs[64][40];

  const int tid  = threadIdx.x;
  const int wave = tid >> 6;
  const int lane = tid & 63;
  const int quad = lane >> 4;
  const int l16  = lane & 15;
  const int rowBase = blockIdx.x * 128;
  const int colBase = blockIdx.y * 64;

  // staging: thread -> (row = tid>>2, 16B seg = tid&3); A needs rows 0..127 (two
  // pointers), B rows 0..63.
  const int sr = tid >> 2, sseg = tid & 3;
  const unsigned short* aptr0 = A  + (size_t)(rowBase + sr) * NP + sseg * 8;
  const unsigned short* aptr1 = A  + (size_t)(rowBase + 64 + sr) * NP + sseg * 8;
  const unsigned short* bptr  = Bt + (size_t)(colBase + sr) * NP + sseg * 8;

  f32x4 acc[2][4] = {};

  uint4 a0 = *(const uint4*)(aptr0);
  uint4 a1 = *(const uint4*)(aptr1);
  uint4 bv = *(const uint4*)(bptr);

  const int nK = NP / 32;  // 14
  for (int kt = 0; kt < nK; ++kt) {
    __syncthreads();
    *(uint4*)&As[sr][sseg * 8]      = a0;
    *(uint4*)&As[64 + sr][sseg * 8] = a1;
    *(uint4*)&Bs[sr][sseg * 8]      = bv;
    __syncthreads();

    if (kt + 1 < nK) {  // prefetch next tile; overlaps the MFMAs below
      a0 = *(const uint4*)(aptr0 + (kt + 1) * 32);
      a1 = *(const uint4*)(aptr1 + (kt + 1) * 32);
      bv = *(const uint4*)(bptr + (kt + 1) * 32);
    }

    bf16x8 af0 = __builtin_bit_cast(bf16x8, *(const uint4*)&As[wave * 32 + l16][quad * 8]);
    bf16x8 af1 = __builtin_bit_cast(bf16x8, *(const uint4*)&As[wave * 32 + 16 + l16][quad * 8]);
#pragma unroll
    for (int nt = 0; nt < 4; ++nt) {
      bf16x8 bf = __builtin_bit_cast(bf16x8, *(const uint4*)&Bs[nt * 16 + l16][quad * 8]);
      acc[0][nt] = __builtin_amdgcn_mfma_f32_16x16x32_bf16(af0, bf, acc[0][nt], 0, 0, 0);
      acc[1][nt] = __builtin_amdgcn_mfma_f32_16x16x32_bf16(af1, bf, acc[1][nt], 0, 0, 0);
    }
  }

  float wsum[2][4] = {};
#pragma unroll
  for (int mt = 0; mt < 2; ++mt) {
#pragma unroll
    for (int nt = 0; nt < 4; ++nt) {
      int col = colBase + nt * 16 + l16;
      float bz = bias[col];
      float wv = wout[col];
#pragma unroll
      for (int r = 0; r < 4; ++r) {
        float v = acc[mt][nt][r] + bz;
        v = v > 0.f ? v : 0.f;
        if (!fuse) {
          int row = rowBase + wave * 32 + mt * 16 + quad * 4 + r;
          C[(size_t)row * NP + col] = f2bf(v);
        } else {
          wsum[mt][r] += v * wv;
        }
      }
    }
  }

  if (fuse) {
#pragma unroll
    for (int mt = 0; mt < 2; ++mt) {
#pragma unroll
      for (int r = 0; r < 4; ++r) {
        float s = wsum[mt][r];
        s += __shfl_xor(s, 1, 64);
        s += __shfl_xor(s, 2, 64);
        s += __shfl_xor(s, 4, 64);
        s += __shfl_xor(s, 8, 64);
        if (l16 == 0) {
          int row = rowBase + wave * 32 + mt * 16 + quad * 4 + r;
          atomicAdd(out + row, s);
        }
      }
    }
  }
}

// ---------------------------------------------------------------------------
extern "C" void kernel_launch(void* const* d_in, const int* in_sizes, int n_in,
                              void* d_out, int out_size, void* d_ws, size_t ws_size,
                              hipStream_t stream) {
  const int*   Xs   = (const int*)d_in[0];
  const float* Xd   = (const float*)d_in[1];
  const float* emb1 = (const float*)d_in[2];
  const float* emb2 = (const float*)d_in[3];
  const float* linw = (const float*)d_in[4];
  const float* bias = (const float*)d_in[5];
  const float* W0   = (const float*)d_in[6];
  const float* b0   = (const float*)d_in[7];
  const float* W1   = (const float*)d_in[8];
  const float* b1   = (const float*)d_in[9];
  const float* W2   = (const float*)d_in[10];
  const float* b2   = (const float*)d_in[11];
  const float* Wout = (const float*)d_in[12];
  float* out = (float*)d_out;

  char* ws = (char*)d_ws;
  const size_t PSZ = (size_t)B_ * NP * 2;        // 14,680,064
  const size_t WSZ = (size_t)NP * NP * 2;        // 401,408
  unsigned short* P0  = (unsigned short*)(ws);
  unsigned short* P1  = (unsigned short*)(ws + PSZ);
  unsigned short* W0t = (unsigned short*)(ws + 2 * PSZ);
  unsigned short* W1t = (unsigned short*)(ws + 2 * PSZ + WSZ);
  unsigned short* W2t = (unsigned short*)(ws + 2 * PSZ + 2 * WSZ);
  float* b0p   = (float*)(ws + 2 * PSZ + 3 * WSZ);
  float* b1p   = (float*)(ws + 2 * PSZ + 3 * WSZ + 1792);
  float* b2p   = (float*)(ws + 2 * PSZ + 3 * WSZ + 2 * 1792);
  float* woutp = (float*)(ws + 2 * PSZ + 3 * WSZ + 3 * 1792);

  fm_kernel<<<B_ / 16, 256, 0, stream>>>(Xs, Xd, emb1, emb2, linw, bias, P0, out);

  conv_all<<<(3 * NP * NP + 4 * NP) / 256, 256, 0, stream>>>(
      W0, W1, W2, b0, b1, b2, Wout, W0t, W1t, W2t, b0p, b1p, b2p, woutp);

  dim3 grid(B_ / 128, NP / 64);
  gemm_relu<<<grid, 256, 0, stream>>>(P0, W0t, b0p, P1, woutp, out, 0);  // h0
  gemm_relu<<<grid, 256, 0, stream>>>(P1, W1t, b1p, P0, woutp, out, 0);  // h1
  gemm_relu<<<grid, 256, 0, stream>>>(P0, W2t, b2p, P1, woutp, out, 1);  // h2 + dot
}

// Round 3
// 284.457 us; speedup vs baseline: 1.1676x; 1.0441x over previous
//
#include <hip/hip_runtime.h>
#include <hip/hip_bf16.h>

// Problem constants
#define B_     16384
#define NS_    26
#define ND_    13
#define V_     100000
#define H_     400
#define NP     448     // padded N and K for every DNN layer
#define K0A    429     // actual DNN_IN
#define MT     64      // rows per fused block
#define ASTR   456     // act LDS row stride in shorts (448 + 8 pad)
#define WCH    (448 * 32)                       // shorts per W k-chunk
#define LDSB   (MT * ASTR * 2 + 2 * WCH * 2)    // 58368 + 57344 = 115712 B

typedef __bf16 bf16x8 __attribute__((ext_vector_type(8)));
typedef float  f32x4  __attribute__((ext_vector_type(4)));

__device__ __forceinline__ unsigned short f2bf(float f) {
  __hip_bfloat16 h = __float2bfloat16(f);
  return __builtin_bit_cast(unsigned short, h);
}

// ---------------------------------------------------------------------------
// prep kernel: blocks [0,1024) do the FM part + build bf16 dnn_in[16384][448];
// blocks [1024, 3383) transpose/pad the three weight matrices to bf16
// [448][448] (Wt[n*448+k] = W[k*400+n]) and pad biases + W_out to 448 fp32.
// ---------------------------------------------------------------------------
__global__ __launch_bounds__(256) void prep_kernel(
    const int* __restrict__ Xs, const float* __restrict__ Xd,
    const float* __restrict__ emb1, const float* __restrict__ emb2,
    const float* __restrict__ linw, const float* __restrict__ bias,
    const float* __restrict__ W0, const float* __restrict__ W1,
    const float* __restrict__ W2, const float* __restrict__ b0,
    const float* __restrict__ b1, const float* __restrict__ b2,
    const float* __restrict__ Wout,
    unsigned short* __restrict__ dnn, unsigned short* __restrict__ W0t,
    unsigned short* __restrict__ W1t, unsigned short* __restrict__ W2t,
    float* __restrict__ b0p, float* __restrict__ b1p, float* __restrict__ b2p,
    float* __restrict__ woutp, float* __restrict__ out) {
  const int blk = blockIdx.x;
  if (blk < 1024) {
    // ---- FM + dnn_in build: 16 lanes per batch row ----
    const int row  = blk * 16 + (threadIdx.x >> 4);
    const int lane = threadIdx.x & 15;
    const int* xs = Xs + row * NS_;
    unsigned short* drow = dnn + (size_t)row * NP;

    float s_sum = 0.f, s_sq = 0.f;
#pragma unroll
    for (int f = 0; f < NS_; ++f) {
      int idx = xs[f];
      float v = emb2[((size_t)f * V_ + idx) * 16 + lane];
      s_sum += v;
      s_sq  += v * v;
      drow[f * 16 + lane] = f2bf(v);
    }
    float lin = 0.f;
    for (int f = lane; f < NS_; f += 16)
      lin += emb1[(size_t)f * V_ + xs[f]];
    float xdv = 0.f;
    if (lane < ND_) {
      xdv = Xd[row * ND_ + lane];
      lin += xdv * linw[lane];
    }
    drow[416 + lane] = f2bf(lane < ND_ ? xdv : 0.f);
    drow[432 + lane] = 0;

    float r = 0.5f * (s_sum * s_sum - s_sq) + lin;
#pragma unroll
    for (int m = 8; m >= 1; m >>= 1) r += __shfl_xor(r, m, 64);
    if (lane == 0) out[row] = r + bias[0];
  } else {
    // ---- weight/bias conversion, n-major (coalesced writes) ----
    const int WSZ = NP * NP;
    int i = (blk - 1024) * 256 + threadIdx.x;
    if (i < 3 * WSZ) {
      int which = i / WSZ;
      int j = i - which * WSZ;
      int n = j / NP, k = j - (j / NP) * NP;
      const float* W = (which == 0) ? W0 : (which == 1) ? W1 : W2;
      unsigned short* Wt = (which == 0) ? W0t : (which == 1) ? W1t : W2t;
      int Kact = (which == 0) ? K0A : H_;
      float v = (k < Kact && n < H_) ? W[k * H_ + n] : 0.f;
      Wt[(size_t)n * NP + k] = f2bf(v);
    } else {
      int j = i - 3 * WSZ;
      if (j < NP)          b0p[j]            = (j < H_) ? b0[j] : 0.f;
      else if (j < 2 * NP) b1p[j - NP]       = (j - NP < H_) ? b1[j - NP] : 0.f;
      else if (j < 3 * NP) b2p[j - 2 * NP]   = (j - 2 * NP < H_) ? b2[j - 2 * NP] : 0.f;
      else if (j < 4 * NP) woutp[j - 3 * NP] = (j - 3 * NP < H_) ? Wout[j - 3 * NP] : 0.f;
    }
  }
}

// ---------------------------------------------------------------------------
// Fused DNN: each block owns 64 batch rows; activation tile [64][448] lives in
// LDS and is updated in place across the 3 layers. Weight k-chunks [448][32]
// stream through a double-buffered LDS region via global_load_lds width=16.
// Layer 2's epilogue fuses the h2 . W_out dot (atomicAdd into out).
// ---------------------------------------------------------------------------
__device__ __forceinline__ void stage_w_chunk(
    const unsigned short* __restrict__ Wt, int kt, unsigned short* wb,
    int wave, int lane) {
#pragma unroll
  for (int i = 0; i < 7; ++i) {
    int sbase = i * 256 + wave * 64;      // wave-uniform 16B-slot base
    int s = sbase + lane;
    int n = s >> 2, g = s & 3;            // slot -> (n row, 16B granule)
    const unsigned short* gp = Wt + n * NP + kt * 32 + g * 8;
    unsigned short* lp = wb + (size_t)sbase * 8;
    __builtin_amdgcn_global_load_lds(
        (const __attribute__((address_space(1))) unsigned int*)gp,
        (__attribute__((address_space(3))) unsigned int*)lp, 16, 0, 0);
  }
}

__global__ __launch_bounds__(256, 1) void fused_dnn(
    const unsigned short* __restrict__ dnn,
    const unsigned short* __restrict__ W0t, const unsigned short* __restrict__ W1t,
    const unsigned short* __restrict__ W2t,
    const float* __restrict__ b0p, const float* __restrict__ b1p,
    const float* __restrict__ b2p, const float* __restrict__ woutp,
    float* __restrict__ out) {
  extern __shared__ char smem[];
  unsigned short* act  = (unsigned short*)smem;                  // [64][456]
  unsigned short* wbuf = (unsigned short*)(smem + MT * ASTR * 2); // [2][WCH]

  const int tid  = threadIdx.x;
  const int wave = tid >> 6;
  const int lane = tid & 63;
  const int quad = lane >> 4;
  const int l16  = lane & 15;
  const int r0   = blockIdx.x * MT;

  // ---- stage dnn_in rows r0..r0+63 into act (7 x 16B per thread) ----
#pragma unroll
  for (int i = 0; i < 7; ++i) {
    int s = i * 256 + tid;
    int row = s / 28, gc = s - (s / 28) * 28;
    uint4 v = *(const uint4*)(dnn + (size_t)(r0 + row) * NP + gc * 8);
    *(uint4*)(act + row * ASTR + gc * 8) = v;
  }

  const unsigned short* Wl[3] = {W0t, W1t, W2t};
  const float* bl[3] = {b0p, b1p, b2p};

  // prefetch layer-0 chunk 0
  stage_w_chunk(Wl[0], 0, wbuf, wave, lane);

  for (int layer = 0; layer < 3; ++layer) {
    const unsigned short* Wt = Wl[layer];
    f32x4 acc[4][7] = {};

    for (int kt = 0; kt < 14; ++kt) {
      __syncthreads();  // drains vmcnt (chunk kt resident) + lgkm; frees other buf
      if (kt + 1 < 14)
        stage_w_chunk(Wt, kt + 1, wbuf + ((kt + 1) & 1) * WCH, wave, lane);
      const unsigned short* wb = wbuf + (kt & 1) * WCH;

      bf16x8 af[4];
#pragma unroll
      for (int mt = 0; mt < 4; ++mt)
        af[mt] = __builtin_bit_cast(
            bf16x8, *(const uint4*)(act + (mt * 16 + l16) * ASTR + kt * 32 + quad * 8));
#pragma unroll
      for (int nt = 0; nt < 7; ++nt) {
        int n = wave * 112 + nt * 16 + l16;
        bf16x8 bf = __builtin_bit_cast(bf16x8, *(const uint4*)(wb + n * 32 + quad * 8));
#pragma unroll
        for (int mt = 0; mt < 4; ++mt)
          acc[mt][nt] = __builtin_amdgcn_mfma_f32_16x16x32_bf16(af[mt], bf, acc[mt][nt], 0, 0, 0);
      }
    }

    __syncthreads();  // all waves done reading act before epilogue writes

    if (layer < 2) {
      // prefetch next layer's chunk 0 (overlaps epilogue)
      stage_w_chunk(Wl[layer + 1], 0, wbuf, wave, lane);
#pragma unroll
      for (int nt = 0; nt < 7; ++nt) {
        int col = wave * 112 + nt * 16 + l16;
        float bz = bl[layer][col];
#pragma unroll
        for (int mt = 0; mt < 4; ++mt) {
#pragma unroll
          for (int r = 0; r < 4; ++r) {
            float v = acc[mt][nt][r] + bz;
            v = v > 0.f ? v : 0.f;
            act[(mt * 16 + quad * 4 + r) * ASTR + col] = f2bf(v);
          }
        }
      }
    } else {
      // fused h2 . wout
      float wsum[4][4] = {};
#pragma unroll
      for (int nt = 0; nt < 7; ++nt) {
        int col = wave * 112 + nt * 16 + l16;
        float bz = bl[2][col];
        float wv = woutp[col];
#pragma unroll
        for (int mt = 0; mt < 4; ++mt) {
#pragma unroll
          for (int r = 0; r < 4; ++r) {
            float v = acc[mt][nt][r] + bz;
            v = v > 0.f ? v : 0.f;
            wsum[mt][r] += v * wv;
          }
        }
      }
#pragma unroll
      for (int mt = 0; mt < 4; ++mt) {
#pragma unroll
        for (int r = 0; r < 4; ++r) {
          float s = wsum[mt][r];
          s += __shfl_xor(s, 1, 64);
          s += __shfl_xor(s, 2, 64);
          s += __shfl_xor(s, 4, 64);
          s += __shfl_xor(s, 8, 64);
          if (l16 == 0)
            atomicAdd(out + r0 + mt * 16 + quad * 4 + r, s);
        }
      }
    }
  }
}

// ---------------------------------------------------------------------------
extern "C" void kernel_launch(void* const* d_in, const int* in_sizes, int n_in,
                              void* d_out, int out_size, void* d_ws, size_t ws_size,
                              hipStream_t stream) {
  const int*   Xs   = (const int*)d_in[0];
  const float* Xd   = (const float*)d_in[1];
  const float* emb1 = (const float*)d_in[2];
  const float* emb2 = (const float*)d_in[3];
  const float* linw = (const float*)d_in[4];
  const float* bias = (const float*)d_in[5];
  const float* W0   = (const float*)d_in[6];
  const float* b0   = (const float*)d_in[7];
  const float* W1   = (const float*)d_in[8];
  const float* b1   = (const float*)d_in[9];
  const float* W2   = (const float*)d_in[10];
  const float* b2   = (const float*)d_in[11];
  const float* Wout = (const float*)d_in[12];
  float* out = (float*)d_out;

  char* ws = (char*)d_ws;
  const size_t PSZ = (size_t)B_ * NP * 2;   // dnn_in: 14,680,064 B
  const size_t WSZ = (size_t)NP * NP * 2;   // each Wt: 401,408 B
  unsigned short* P0  = (unsigned short*)(ws);
  unsigned short* W0t = (unsigned short*)(ws + PSZ);
  unsigned short* W1t = (unsigned short*)(ws + PSZ + WSZ);
  unsigned short* W2t = (unsigned short*)(ws + PSZ + 2 * WSZ);
  float* b0p   = (float*)(ws + PSZ + 3 * WSZ);
  float* b1p   = (float*)(ws + PSZ + 3 * WSZ + 1792);
  float* b2p   = (float*)(ws + PSZ + 3 * WSZ + 2 * 1792);
  float* woutp = (float*)(ws + PSZ + 3 * WSZ + 3 * 1792);

  (void)hipFuncSetAttribute((const void*)fused_dnn,
                            hipFuncAttributeMaxDynamicSharedMemorySize, LDSB);

  // fm blocks: 1024; conv blocks: ceil((3*448*448 + 4*448)/256) = 2359
  prep_kernel<<<1024 + 2359, 256, 0, stream>>>(
      Xs, Xd, emb1, emb2, linw, bias, W0, W1, W2, b0, b1, b2, Wout,
      P0, W0t, W1t, W2t, b0p, b1p, b2p, woutp, out);

  fused_dnn<<<B_ / MT, 256, LDSB, stream>>>(
      P0, W0t, W1t, W2t, b0p, b1p, b2p, woutp, out);
}